// Round 5
// baseline (571.305 us; speedup 1.0000x reference)
//
#include <hip/hip_runtime.h>
#include <cstdint>
#include <cstddef>

typedef __bf16 bf16;
typedef __attribute__((ext_vector_type(8))) __bf16 bf16x8;
typedef __attribute__((ext_vector_type(4))) float f32x4;
typedef __attribute__((ext_vector_type(4))) unsigned int u32x4;

#define QN 2048

__device__ __forceinline__ float sigmoidf_(float v) {
  return 1.0f / (1.0f + __expf(-v));
}

__device__ __forceinline__ bf16x8 cvt8(const float* p) {
  const f32x4* p4 = (const f32x4*)p;
  f32x4 lo = p4[0], hi = p4[1];
  bf16x8 r;
#pragma unroll
  for (int j = 0; j < 4; ++j) {
    r[j] = (bf16)lo[j];
    r[j + 4] = (bf16)hi[j];
  }
  return r;
}

// ---------------- copy: out = x (neighbor rows are passthrough) --------------
__global__ __launch_bounds__(256) void copy_ker(const u32x4* __restrict__ in,
                                                u32x4* __restrict__ out, int n) {
  int i = blockIdx.x * 256 + threadIdx.x;
  if (i < n) out[i] = in[i];
}

// ---------------- GEMM core --------------------------------------------------
// C[M x 256] = EPI( A[M x K] @ W[256 x K]^T + bias ), W/x/bias are f32 global,
// A is bf16 ws (AMODE 0) or generated/converted f32 (AMODE 1..4).
// block = 256 thr (4 waves), tile 64(M) x 256(N), BK = 32, mfma 16x16x32 bf16.
// AMODE: 0=bf16 ws A | 1=generate sine-embed pe (K=768) | 2=x neighbor rows
//        3=x ego rows | 4=fp32 ego ws
// EPI:   0=relu->bf16 | 1=+x_neigh->bf16 (kk) | 2=bf16 | 3=ego1=4*(x_ego+v)->f32
//        4=out_ego=4*(egoPrev+v)->f32 out | 5=f32 (qp)
template <int AMODE, int EPI, int KDIM>
__global__ __launch_bounds__(256) void gemm_ker(
    const bf16* __restrict__ A, const float* __restrict__ Af,
    const float* __restrict__ W, const float* __restrict__ bias,
    const float* __restrict__ x, const float* __restrict__ rp,
    const float* __restrict__ pm, const float* __restrict__ egoPrev,
    bf16* __restrict__ outB, float* __restrict__ outF) {
  // +8 pad (40 bf16 = 80 B rows): keeps 16B alignment, b128 reads at bank floor
  __shared__ bf16 As[64][40];
  __shared__ bf16 Bs[256][40];

  const int tid = threadIdx.x;
  const int arow = tid >> 2;    // 0..63  : A row staged by this thread
  const int achunk = tid & 3;   // 0..3   : 8-elem k-chunk
  const int rg_ = blockIdx.x * 64 + arow;

  const bf16* aptr = nullptr;
  const float* afptr = nullptr;
  float tr0 = 0.f, tr1 = 0.f, tr2 = 0.f;
  if constexpr (AMODE == 0) {
    aptr = A + (size_t)rg_ * KDIM + achunk * 8;
  } else if constexpr (AMODE == 1) {
    // neighbor row -> (b, j, q); trans = sigmoid(T[0:3,:] @ [ref,1])
    int b = rg_ >> 13, j = (rg_ >> 11) & 3, q = rg_ & 2047;
    int t = b * 5 + 1 + j;
    const float* rpp = rp + ((size_t)t * QN + q) * 3;
    float r0 = rpp[0] * 281.6f - 140.8f;
    float r1 = rpp[1] * 80.0f - 40.0f;
    float r2 = rpp[2] * 4.0f - 3.0f;
    const float* T = pm + (size_t)(b * 5 + 1 + j) * 80;  // [b][t][0][.][.]
    tr0 = sigmoidf_(T[0] * r0 + T[1] * r1 + T[2] * r2 + T[3]);
    tr1 = sigmoidf_(T[4] * r0 + T[5] * r1 + T[6] * r2 + T[7]);
    tr2 = sigmoidf_(T[8] * r0 + T[9] * r1 + T[10] * r2 + T[11]);
  } else if constexpr (AMODE == 2) {
    int b = rg_ >> 13, j = (rg_ >> 11) & 3, q = rg_ & 2047;
    afptr = x + (((size_t)q * 40 + b * 5 + 1 + j) << 8) + achunk * 8;
  } else if constexpr (AMODE == 3) {
    int b = rg_ >> 11, q = rg_ & 2047;
    afptr = x + (((size_t)q * 40 + b * 5) << 8) + achunk * 8;
  } else if constexpr (AMODE == 4) {
    afptr = Af + (size_t)rg_ * 256 + achunk * 8;
  }

  const float* wptr = W + (size_t)tid * KDIM;  // thread stages W row `tid`

  const int wave = tid >> 6;
  const int lane = tid & 63;
  const int m16 = lane & 15;
  const int quad = lane >> 4;

  f32x4 acc[4][4] = {};

  for (int k0 = 0; k0 < KDIM; k0 += 32) {
    // ---- stage A tile (64 x 32) ----
    bf16x8 av;
    if constexpr (AMODE == 1) {
      int c = k0 >> 8;
      float tc = (c == 0) ? tr0 : (c == 1 ? tr1 : tr2);
      int fbase = (k0 & 255) + achunk * 8;
#pragma unroll
      for (int jj = 0; jj < 8; ++jj) {
        int f = fbase + jj;
        int ti = f >> 1;
        // 10000^(-ti/128) = 2^(-ti * log2(10000)/128)
        float freq = exp2f((float)ti * -0.10381025296522975f);
        float ang = tc * 6.283185307179586f * freq;
        float v = (f & 1) ? __cosf(ang) : __sinf(ang);
        av[jj] = (bf16)v;
      }
    } else if constexpr (AMODE == 0) {
      av = *(const bf16x8*)(aptr + k0);
    } else {
      av = cvt8(afptr + k0);
    }
    *(bf16x8*)(&As[arow][achunk * 8]) = av;
    // ---- stage B tile (256 x 32): thread t converts 32 f32 of W row t ----
#pragma unroll
    for (int c2 = 0; c2 < 4; ++c2)
      *(bf16x8*)(&Bs[tid][c2 * 8]) = cvt8(wptr + k0 + c2 * 8);
    __syncthreads();

    // ---- fragments + mfma ----
    bf16x8 afr[4], bfr[4];
#pragma unroll
    for (int mt = 0; mt < 4; ++mt)
      afr[mt] = *(const bf16x8*)(&As[mt * 16 + m16][quad * 8]);
#pragma unroll
    for (int nt = 0; nt < 4; ++nt)
      bfr[nt] = *(const bf16x8*)(&Bs[wave * 64 + nt * 16 + m16][quad * 8]);
#pragma unroll
    for (int mt = 0; mt < 4; ++mt)
#pragma unroll
      for (int nt = 0; nt < 4; ++nt)
        acc[mt][nt] = __builtin_amdgcn_mfma_f32_16x16x32_bf16(
            afr[mt], bfr[nt], acc[mt][nt], 0, 0, 0);
    __syncthreads();
  }

  // ---- epilogue: D row = quad*4+reg, col = lane&15 ----
#pragma unroll
  for (int mt = 0; mt < 4; ++mt) {
#pragma unroll
    for (int nt = 0; nt < 4; ++nt) {
      const int col = wave * 64 + nt * 16 + m16;
      const float bv = bias[col];
#pragma unroll
      for (int rg2 = 0; rg2 < 4; ++rg2) {
        const int r = blockIdx.x * 64 + mt * 16 + quad * 4 + rg2;
        float v = acc[mt][nt][rg2] + bv;
        if constexpr (EPI == 0) {
          v = fmaxf(v, 0.0f);
          outB[(size_t)r * 256 + col] = (bf16)v;
        } else if constexpr (EPI == 1) {
          int b = r >> 13, j = (r >> 11) & 3, q = r & 2047;
          v += x[(((size_t)q * 40 + b * 5 + 1 + j) << 8) + col];
          outB[(size_t)r * 256 + col] = (bf16)v;
        } else if constexpr (EPI == 2) {
          outB[(size_t)r * 256 + col] = (bf16)v;
        } else if constexpr (EPI == 3) {
          int b = r >> 11, q = r & 2047;
          float xe = x[(((size_t)q * 40 + b * 5) << 8) + col];
          outF[(size_t)r * 256 + col] = 4.0f * (xe + v);
        } else if constexpr (EPI == 4) {
          int b = r >> 11, q = r & 2047;
          float e1 = egoPrev[(size_t)r * 256 + col];
          outF[(((size_t)q * 40 + b * 5) << 8) + col] = 4.0f * (e1 + v);
        } else if constexpr (EPI == 5) {
          outF[(size_t)r * 256 + col] = v;
        }
      }
    }
  }
}

// ---------------- attention: 4-way softmax per (q-row, head) -----------------
__global__ __launch_bounds__(256) void attn_ker(const float* __restrict__ qp,
                                                const bf16* __restrict__ kp,
                                                const bf16* __restrict__ vp,
                                                bf16* __restrict__ o) {
  int p = blockIdx.x * 256 + threadIdx.x;  // 16384 rows * 8 heads
  int h = p & 7;
  int re = p >> 3;
  int b = re >> 11;
  int q = re & 2047;
  const f32x4* qpv = (const f32x4*)(qp + ((size_t)re << 8) + h * 32);
  float qv[32];
#pragma unroll
  for (int i = 0; i < 8; ++i) {
    f32x4 t = qpv[i];
#pragma unroll
    for (int j = 0; j < 4; ++j) qv[i * 4 + j] = t[j];
  }
  size_t base = ((size_t)(b * 4) * QN + q) * 256 + h * 32;
  float s[4];
#pragma unroll
  for (int m = 0; m < 4; ++m) {
    const bf16x8* kv = (const bf16x8*)(kp + base + (size_t)m * (QN * 256));
    float a = 0.f;
#pragma unroll
    for (int i = 0; i < 4; ++i) {
      bf16x8 t = kv[i];
#pragma unroll
      for (int j = 0; j < 8; ++j) a += qv[i * 8 + j] * (float)t[j];
    }
    s[m] = a * 0.17677669529663687f;  // 1/sqrt(32)
  }
  float mx = fmaxf(fmaxf(s[0], s[1]), fmaxf(s[2], s[3]));
  float e0 = __expf(s[0] - mx), e1 = __expf(s[1] - mx);
  float e2 = __expf(s[2] - mx), e3 = __expf(s[3] - mx);
  float inv = 1.0f / (e0 + e1 + e2 + e3);
  float w[4] = {e0 * inv, e1 * inv, e2 * inv, e3 * inv};
  float ov[32] = {};
#pragma unroll
  for (int m = 0; m < 4; ++m) {
    const bf16x8* vv = (const bf16x8*)(vp + base + (size_t)m * (QN * 256));
#pragma unroll
    for (int i = 0; i < 4; ++i) {
      bf16x8 t = vv[i];
#pragma unroll
      for (int j = 0; j < 8; ++j) ov[i * 8 + j] += w[m] * (float)t[j];
    }
  }
  bf16x8* op = (bf16x8*)(o + ((size_t)re << 8) + h * 32);
#pragma unroll
  for (int i = 0; i < 4; ++i) {
    bf16x8 t;
#pragma unroll
    for (int j = 0; j < 8; ++j) t[j] = (bf16)ov[i * 8 + j];
    op[i] = t;
  }
}

extern "C" void kernel_launch(void* const* d_in, const int* in_sizes, int n_in,
                              void* d_out, int out_size, void* d_ws, size_t ws_size,
                              hipStream_t stream) {
  (void)n_in; (void)out_size; (void)ws_size;
  const float* x   = (const float*)d_in[0];   // (2048, 40, 256) f32
  const float* rp  = (const float*)d_in[1];   // (40, 2048, 3) f32
  const float* pm  = (const float*)d_in[2];   // (8, 5, 5, 4, 4) f32

  // record_len (8 elems) sits at index 3 in setup_inputs() dict order; weight
  // tensors are contiguous from wbase in either convention.
  const int wbase = (in_sizes[3] == 8) ? 4 : 3;
  const float* ipw = (const float*)d_in[wbase + 0];  // (768, 256)
  const float* ipb = (const float*)d_in[wbase + 1];  // (768,)
  const float* ow  = (const float*)d_in[wbase + 2];  // (256, 256)
  const float* obv = (const float*)d_in[wbase + 3];  // (256,)
  const float* w1  = (const float*)d_in[wbase + 4];  // (256, 768)
  const float* b1  = (const float*)d_in[wbase + 5];
  const float* w2  = (const float*)d_in[wbase + 6];  // (256, 256)
  const float* b2  = (const float*)d_in[wbase + 7];
  float* out = (float*)d_out;
  char* ws = (char*)d_ws;

  // ws layout (128 MB total, regions reused once dead):
  bf16* h   = (bf16*)(ws + 0);          // 32 MB, dead after kk GEMM
  bf16* kk  = (bf16*)(ws + 33554432);   // 32 MB, dead after kp GEMM
  bf16* kp  = (bf16*)(ws + 67108864);   // 32 MB, live
  bf16* vp  = (bf16*)(ws + 100663296);  // 32 MB, live
  float* qp = (float*)(ws + 0);         // 16 MB, reuses h region
  bf16* oo  = (bf16*)(ws + 16777216);   // 8 MB, reuses h region
  float* ego = (float*)(ws + 33554432); // 16 MB, reuses kk region

  // 1) out = x (f32, 83.9 MB; ego rows overwritten at the end)
  copy_ker<<<20480, 256, 0, stream>>>((const u32x4*)x, (u32x4*)out, 5242880);
  // 2) h = relu(pe @ w1^T + b1)    [pe generated on the fly]
  gemm_ker<1, 0, 768><<<1024, 256, 0, stream>>>(nullptr, nullptr, w1, b1, x, rp, pm, nullptr, h, nullptr);
  // 3) kk = x_neigh + (h @ w2^T + b2)
  gemm_ker<0, 1, 256><<<1024, 256, 0, stream>>>(h, nullptr, w2, b2, x, rp, pm, nullptr, kk, nullptr);
  // 4) kp = kk @ Wk^T + bk
  gemm_ker<0, 2, 256><<<1024, 256, 0, stream>>>(kk, nullptr, ipw + 65536, ipb + 256, x, rp, pm, nullptr, kp, nullptr);
  // 5) vp = x_neigh @ Wv^T + bv
  gemm_ker<2, 2, 256><<<1024, 256, 0, stream>>>(nullptr, nullptr, ipw + 131072, ipb + 512, x, rp, pm, nullptr, vp, nullptr);
  // --- iteration 1 ---
  gemm_ker<3, 5, 256><<<256, 256, 0, stream>>>(nullptr, nullptr, ipw, ipb, x, rp, pm, nullptr, nullptr, qp);
  attn_ker<<<512, 256, 0, stream>>>(qp, kp, vp, oo);
  gemm_ker<0, 3, 256><<<256, 256, 0, stream>>>(oo, nullptr, ow, obv, x, rp, pm, nullptr, nullptr, ego);
  // --- iteration 2 ---
  gemm_ker<4, 5, 256><<<256, 256, 0, stream>>>(nullptr, ego, ipw, ipb, x, rp, pm, nullptr, nullptr, qp);
  attn_ker<<<512, 256, 0, stream>>>(qp, kp, vp, oo);
  gemm_ker<0, 4, 256><<<256, 256, 0, stream>>>(oo, nullptr, ow, obv, x, rp, pm, ego, nullptr, out);
}

// Round 6
// 387.240 us; speedup vs baseline: 1.4753x; 1.4753x over previous
//
#include <hip/hip_runtime.h>
#include <cstdint>
#include <cstddef>

typedef __bf16 bf16;
typedef __attribute__((ext_vector_type(8))) __bf16 bf16x8;
typedef __attribute__((ext_vector_type(4))) float f32x4;
typedef __attribute__((ext_vector_type(4))) unsigned int u32x4;

#define QN 2048

__device__ __forceinline__ float sigmoidf_(float v) { return 1.0f / (1.0f + __expf(-v)); }

__device__ __forceinline__ bf16x8 cvt8(const float* p) {
  const f32x4* p4 = (const f32x4*)p;
  f32x4 lo = p4[0], hi = p4[1];
  bf16x8 r;
#pragma unroll
  for (int j = 0; j < 4; ++j) { r[j] = (bf16)lo[j]; r[j + 4] = (bf16)hi[j]; }
  return r;
}

// async global->LDS, 16B per lane; LDS dest = wave-uniform base + lane*16
__device__ __forceinline__ void load_lds16(const bf16* g, bf16* l) {
  __builtin_amdgcn_global_load_lds(
      (const __attribute__((address_space(1))) void*)g,
      (__attribute__((address_space(3))) void*)l, 16, 0, 0);
}

// ---------------- copy: out = x (neighbor rows passthrough) ------------------
__global__ __launch_bounds__(256) void copy_ker(const u32x4* __restrict__ in,
                                                u32x4* __restrict__ out, int n) {
  int i = blockIdx.x * 256 + threadIdx.x;
  if (i < n) out[i] = in[i];
}

// ---------------- convert all weights f32 -> bf16 into wb --------------------
// layout in wb: [0,196608) ipw | [196608,262144) ow | [262144,458752) w1 | [458752,524288) w2
__global__ __launch_bounds__(256) void cvtw_ker(const float* __restrict__ ipw,
                                                const float* __restrict__ ow,
                                                const float* __restrict__ w1,
                                                const float* __restrict__ w2,
                                                bf16* __restrict__ wb) {
  int e = (blockIdx.x * 256 + threadIdx.x) * 8;
  const float* src; int off;
  if (e < 196608)      { src = ipw; off = e; }
  else if (e < 262144) { src = ow;  off = e - 196608; }
  else if (e < 458752) { src = w1;  off = e - 262144; }
  else                 { src = w2;  off = e - 458752; }
  *(bf16x8*)(wb + e) = cvt8(src + off);
}

// ---------------- GEMM core (m97-style) --------------------------------------
// C[M x 256] = EPI( A[M x K] @ W[256 x K]^T + bias )
// 256 thr = 4 waves (2x2), tile 128(M) x 128(N), BK=32, mfma 16x16x32 bf16.
// B-tile: bf16 W via global_load_lds (unpadded Bs). A-tile: register-staged
// into padded As (80 B stride: writes & b128 reads at bank floor).
// AMODE: 0=bf16 ws A | 1=generate sine-embed pe (K=768) | 2=x neigh rows (f32)
//        3=x ego rows (f32) | 4=f32 ws rows (egoF)
// EPI:   0=relu->bf16 | 1=+x_neigh->bf16 | 2=bf16 | 3=4*(x_ego+v)->f32 egoF
//        4=4*(egoPrev+v)->f32 out(ego rows)
template <int AMODE, int EPI, int KDIM>
__global__ __launch_bounds__(256) void gemm_ker(
    const bf16* __restrict__ A, const float* __restrict__ Af,
    const bf16* __restrict__ W, const float* __restrict__ bias,
    const float* __restrict__ x, const float* __restrict__ rp,
    const float* __restrict__ pm, const float* __restrict__ egoPrev,
    bf16* __restrict__ outB, float* __restrict__ outF) {
  __shared__ bf16 As[128][40];  // +8 pad: 80 B stride
  __shared__ bf16 Bs[128][32];  // unpadded: global_load_lds order

  const int tid = threadIdx.x;
  const int bidm = blockIdx.x >> 1;
  const int bidn = blockIdx.x & 1;
  const int rowBase = bidm << 7;
  const int colBase = bidn << 7;

  const int wave = tid >> 6, lane = tid & 63;
  const int m16 = lane & 15, quad = lane >> 4;
  const int wr = wave >> 1, wc = wave & 1;

  // A staging: thread t stages row t>>1, 16-elem half (t&1)
  const int sRow = tid >> 1, sHalf = tid & 1;
  const int rgA = rowBase + sRow;

  const float* afp = nullptr;
  float tr0 = 0.f, tr1 = 0.f, tr2 = 0.f;
  if constexpr (AMODE == 1) {
    int b = rgA >> 13, j = (rgA >> 11) & 3, q = rgA & 2047;
    int t = b * 5 + 1 + j;
    const float* rpp = rp + ((size_t)t * QN + q) * 3;
    float r0 = rpp[0] * 281.6f - 140.8f;
    float r1 = rpp[1] * 80.0f - 40.0f;
    float r2 = rpp[2] * 4.0f - 3.0f;
    const float* T = pm + (size_t)t * 80;  // [b][t][0][.][.]
    tr0 = sigmoidf_(T[0] * r0 + T[1] * r1 + T[2] * r2 + T[3]);
    tr1 = sigmoidf_(T[4] * r0 + T[5] * r1 + T[6] * r2 + T[7]);
    tr2 = sigmoidf_(T[8] * r0 + T[9] * r1 + T[10] * r2 + T[11]);
  } else if constexpr (AMODE == 2) {
    int b = rgA >> 13, j = (rgA >> 11) & 3, q = rgA & 2047;
    afp = x + (((size_t)q * 40 + b * 5 + 1 + j) << 8);
  } else if constexpr (AMODE == 3) {
    int b = rgA >> 11, q = rgA & 2047;
    afp = x + (((size_t)q * 40 + b * 5) << 8);
  } else if constexpr (AMODE == 4) {
    afp = Af + (size_t)rgA * 256;
  }

  // B staging: wave stages Bs rows [wave*32, wave*32+32) as 2 x 16-row DMA
  const bf16* wsrc = W + (size_t)(colBase + (wave << 5) + (lane >> 2)) * KDIM + ((lane & 3) << 3);
  bf16* bdst0 = &Bs[(wave << 5)][0];
  bf16* bdst1 = &Bs[(wave << 5) + 16][0];

  f32x4 acc[4][4] = {};

  for (int k0 = 0; k0 < KDIM; k0 += 32) {
    load_lds16(wsrc + k0, bdst0);
    load_lds16(wsrc + (size_t)16 * KDIM + k0, bdst1);

    bf16x8 a0, a1;
    if constexpr (AMODE == 1) {
      int c = k0 >> 8;
      float tc = (c == 0) ? tr0 : (c == 1 ? tr1 : tr2);
      int l0 = (k0 & 255) + (sHalf << 4);
#pragma unroll
      for (int jj = 0; jj < 8; ++jj) {
        int l = l0 + jj, ti = l >> 1;
        float freq = exp2f((float)ti * -0.10381025296522975f);
        float ang = tc * 6.283185307179586f * freq;
        a0[jj] = (bf16)((l & 1) ? __cosf(ang) : __sinf(ang));
      }
#pragma unroll
      for (int jj = 0; jj < 8; ++jj) {
        int l = l0 + 8 + jj, ti = l >> 1;
        float freq = exp2f((float)ti * -0.10381025296522975f);
        float ang = tc * 6.283185307179586f * freq;
        a1[jj] = (bf16)((l & 1) ? __cosf(ang) : __sinf(ang));
      }
    } else if constexpr (AMODE == 0) {
      const bf16* ap = A + (size_t)rgA * KDIM + k0 + (sHalf << 4);
      a0 = ((const bf16x8*)ap)[0];
      a1 = ((const bf16x8*)ap)[1];
    } else {
      const float* fp = afp + k0 + (sHalf << 4);
      a0 = cvt8(fp);
      a1 = cvt8(fp + 8);
    }
    *(bf16x8*)(&As[sRow][sHalf << 4]) = a0;
    *(bf16x8*)(&As[sRow][(sHalf << 4) + 8]) = a1;
    __syncthreads();  // drains vmcnt (DMA) + lgkmcnt (ds_write)

    bf16x8 afr[4], bfr[4];
#pragma unroll
    for (int mt = 0; mt < 4; ++mt)
      afr[mt] = *(const bf16x8*)(&As[(wr << 6) + (mt << 4) + m16][quad << 3]);
#pragma unroll
    for (int nt = 0; nt < 4; ++nt)
      bfr[nt] = *(const bf16x8*)(&Bs[(wc << 6) + (nt << 4) + m16][quad << 3]);
#pragma unroll
    for (int mt = 0; mt < 4; ++mt)
#pragma unroll
      for (int nt = 0; nt < 4; ++nt)
        acc[mt][nt] = __builtin_amdgcn_mfma_f32_16x16x32_bf16(
            afr[mt], bfr[nt], acc[mt][nt], 0, 0, 0);
    __syncthreads();
  }

  // epilogue: row = quad*4+reg (A side), col = m16 (B side)
#pragma unroll
  for (int mt = 0; mt < 4; ++mt) {
#pragma unroll
    for (int nt = 0; nt < 4; ++nt) {
      const int col = colBase + (wc << 6) + (nt << 4) + m16;
      const float bv = bias[col];
#pragma unroll
      for (int rg = 0; rg < 4; ++rg) {
        const int r = rowBase + (wr << 6) + (mt << 4) + (quad << 2) + rg;
        float v = acc[mt][nt][rg] + bv;
        if constexpr (EPI == 0) {
          outB[(size_t)r * 256 + col] = (bf16)fmaxf(v, 0.0f);
        } else if constexpr (EPI == 1) {
          int b = r >> 13, j = (r >> 11) & 3, q = r & 2047;
          v += x[(((size_t)q * 40 + b * 5 + 1 + j) << 8) + col];
          outB[(size_t)r * 256 + col] = (bf16)v;
        } else if constexpr (EPI == 2) {
          outB[(size_t)r * 256 + col] = (bf16)v;
        } else if constexpr (EPI == 3) {
          int b = r >> 11, q = r & 2047;
          float xe = x[(((size_t)q * 40 + b * 5) << 8) + col];
          outF[(size_t)r * 256 + col] = 4.0f * (xe + v);
        } else if constexpr (EPI == 4) {
          int b = r >> 11, q = r & 2047;
          float e1 = egoPrev[(size_t)r * 256 + col];
          outF[(((size_t)q * 40 + b * 5) << 8) + col] = 4.0f * (e1 + v);
        }
      }
    }
  }
}

// ---------------- attention: 4-way softmax per (q-row, head) -----------------
__global__ __launch_bounds__(256) void attn_ker(const bf16* __restrict__ qp,
                                                const bf16* __restrict__ kp,
                                                const bf16* __restrict__ vp,
                                                bf16* __restrict__ o) {
  int p = blockIdx.x * 256 + threadIdx.x;  // 16384 rows * 8 heads
  int h = p & 7;
  int re = p >> 3;
  int b = re >> 11;
  int q = re & 2047;
  const bf16x8* qpv = (const bf16x8*)(qp + ((size_t)re << 8) + h * 32);
  float qv[32];
#pragma unroll
  for (int i = 0; i < 4; ++i) {
    bf16x8 t = qpv[i];
#pragma unroll
    for (int j = 0; j < 8; ++j) qv[i * 8 + j] = (float)t[j];
  }
  size_t base = ((size_t)(b * 4) * QN + q) * 256 + h * 32;
  float s[4];
#pragma unroll
  for (int m = 0; m < 4; ++m) {
    const bf16x8* kv = (const bf16x8*)(kp + base + (size_t)m * (QN * 256));
    float a = 0.f;
#pragma unroll
    for (int i = 0; i < 4; ++i) {
      bf16x8 t = kv[i];
#pragma unroll
      for (int j = 0; j < 8; ++j) a += qv[i * 8 + j] * (float)t[j];
    }
    s[m] = a * 0.17677669529663687f;  // 1/sqrt(32)
  }
  float mx = fmaxf(fmaxf(s[0], s[1]), fmaxf(s[2], s[3]));
  float e0 = __expf(s[0] - mx), e1 = __expf(s[1] - mx);
  float e2 = __expf(s[2] - mx), e3 = __expf(s[3] - mx);
  float inv = 1.0f / (e0 + e1 + e2 + e3);
  float w[4] = {e0 * inv, e1 * inv, e2 * inv, e3 * inv};
  float ov[32] = {};
#pragma unroll
  for (int m = 0; m < 4; ++m) {
    const bf16x8* vv = (const bf16x8*)(vp + base + (size_t)m * (QN * 256));
#pragma unroll
    for (int i = 0; i < 4; ++i) {
      bf16x8 t = vv[i];
#pragma unroll
      for (int j = 0; j < 8; ++j) ov[i * 8 + j] += w[m] * (float)t[j];
    }
  }
  bf16x8* op = (bf16x8*)(o + ((size_t)re << 8) + h * 32);
#pragma unroll
  for (int i = 0; i < 4; ++i) {
    bf16x8 t;
#pragma unroll
    for (int j = 0; j < 8; ++j) t[j] = (bf16)ov[i * 8 + j];
    op[i] = t;
  }
}

extern "C" void kernel_launch(void* const* d_in, const int* in_sizes, int n_in,
                              void* d_out, int out_size, void* d_ws, size_t ws_size,
                              hipStream_t stream) {
  (void)n_in; (void)out_size; (void)ws_size;
  const float* x   = (const float*)d_in[0];   // (2048, 40, 256)
  const float* rp  = (const float*)d_in[1];   // (40, 2048, 3)
  const float* pm  = (const float*)d_in[2];   // (8, 5, 5, 4, 4)
  const int wbase = (in_sizes[3] == 8) ? 4 : 3;  // record_len probe
  const float* ipw = (const float*)d_in[wbase + 0];  // (768, 256)
  const float* ipb = (const float*)d_in[wbase + 1];  // (768,)
  const float* ow  = (const float*)d_in[wbase + 2];  // (256, 256)
  const float* obv = (const float*)d_in[wbase + 3];  // (256,)
  const float* w1  = (const float*)d_in[wbase + 4];  // (256, 768)
  const float* b1  = (const float*)d_in[wbase + 5];
  const float* w2  = (const float*)d_in[wbase + 6];  // (256, 256)
  const float* b2  = (const float*)d_in[wbase + 7];
  float* out = (float*)d_out;
  char* ws = (char*)d_ws;

  // ws regions (101.8 MB of >=128 MiB):
  bf16* h    = (bf16*)(ws + 0);          // 32Mi, L:pe -> kk
  bf16* kk   = (bf16*)(ws + 33554432);   // 32Mi, L:kk -> kp
  bf16* kp   = (bf16*)(ws + 0);          // 32Mi, over dead h; live to attn2
  bf16* vp   = (bf16*)(ws + 67108864);   // 32Mi, live to attn2
  bf16* qp   = (bf16*)(ws + 33554432);   // 8Mi (over dead kk)
  bf16* oo   = (bf16*)(ws + 41943040);   // 8Mi
  float* egoF = (float*)(ws + 50331648); // 16Mi, live to final
  bf16* wb   = (bf16*)(ws + 100663296);  // 1Mi bf16 weights
  const bf16* wq  = wb;
  const bf16* wk  = wb + 65536;
  const bf16* wv  = wb + 131072;
  const bf16* owb = wb + 196608;
  const bf16* w1b = wb + 262144;
  const bf16* w2b = wb + 458752;

  // 1) bf16 weights
  cvtw_ker<<<256, 256, 0, stream>>>(ipw, ow, w1, w2, wb);
  // 2) out = x (ego rows overwritten by final GEMM)
  copy_ker<<<20480, 256, 0, stream>>>((const u32x4*)x, (u32x4*)out, 5242880);
  // 3) h = relu(pe @ w1^T + b1)   [pe generated on the fly]
  gemm_ker<1, 0, 768><<<1024, 256, 0, stream>>>(nullptr, nullptr, w1b, b1, x, rp, pm, nullptr, h, nullptr);
  // 4) kk = x_neigh + (h @ w2^T + b2)
  gemm_ker<0, 1, 256><<<1024, 256, 0, stream>>>(h, nullptr, w2b, b2, x, rp, pm, nullptr, kk, nullptr);
  // 5) kp = kk @ Wk^T + bk   (writes over dead h)
  gemm_ker<0, 2, 256><<<1024, 256, 0, stream>>>(kk, nullptr, wk, ipb + 256, x, rp, pm, nullptr, kp, nullptr);
  // 6) vp = x_neigh @ Wv^T + bv
  gemm_ker<2, 2, 256><<<1024, 256, 0, stream>>>(nullptr, nullptr, wv, ipb + 512, x, rp, pm, nullptr, vp, nullptr);
  // --- iteration 1 ---
  gemm_ker<3, 2, 256><<<256, 256, 0, stream>>>(nullptr, nullptr, wq, ipb, x, rp, pm, nullptr, qp, nullptr);
  attn_ker<<<512, 256, 0, stream>>>(qp, kp, vp, oo);
  gemm_ker<0, 3, 256><<<256, 256, 0, stream>>>(oo, nullptr, owb, obv, x, rp, pm, nullptr, nullptr, egoF);
  // --- iteration 2 ---
  gemm_ker<4, 2, 256><<<256, 256, 0, stream>>>(nullptr, egoF, wq, ipb, x, rp, pm, nullptr, qp, nullptr);
  attn_ker<<<512, 256, 0, stream>>>(qp, kp, vp, oo);
  gemm_ker<0, 4, 256><<<256, 256, 0, stream>>>(oo, nullptr, owb, obv, x, rp, pm, egoF, nullptr, out);
}